// Round 9
// baseline (94.564 us; speedup 1.0000x reference)
//
#include <hip/hip_runtime.h>
#include <hip/hip_bf16.h>
#include <stdint.h>

#define B_ROWS 8192
#define HDIM   1024
#define IDIM   128
#define KDIM   1152
#define TMAX   128

typedef unsigned short u16;
typedef __bf16 bf16x8 __attribute__((ext_vector_type(8)));
typedef float  f32x4  __attribute__((ext_vector_type(4)));

static __device__ __forceinline__ u16 f2bf(float f) {
  union { float f; unsigned u; } v; v.f = f;
  unsigned r = v.u + 0x7FFFu + ((v.u >> 16) & 1u);
  return (u16)(r >> 16);
}
static __device__ __forceinline__ float bf2f(u16 b) {
  union { unsigned u; float f; } v; v.u = ((unsigned)b) << 16; return v.f;
}

template<int N> __device__ __forceinline__ void waitv() {
  if constexpr (N == 8)      asm volatile("s_waitcnt vmcnt(8)" ::: "memory");
  else if constexpr (N == 6) asm volatile("s_waitcnt vmcnt(6)" ::: "memory");
  else if constexpr (N == 2) asm volatile("s_waitcnt vmcnt(2)" ::: "memory");
  else                       asm volatile("s_waitcnt vmcnt(0)" ::: "memory");
}

// ---------------------------------------------------------------------------
// Kernel 1: bf16 conversion/staging (R8 version, verified)
// ---------------------------------------------------------------------------
#define W_CHUNKS  (3*1024*1152/4)
#define H_CHUNKS  (B_ROWS*HDIM/4)
#define X_CHUNKS  (B_ROWS*IDIM/4)
#define W_BLOCKS  (W_CHUNKS/256)
#define H_BLOCKS  (H_CHUNKS/256)
#define X_BLOCKS  (X_CHUNKS/256)
#define CV_BLOCKS (W_BLOCKS + H_BLOCKS + X_BLOCKS)

__global__ __launch_bounds__(256)
void convert_kernel(const float* __restrict__ t,
                    const float* __restrict__ h,
                    const float* __restrict__ xc,
                    const float* __restrict__ Wr,
                    const float* __restrict__ Wz,
                    const float* __restrict__ Wh,
                    u16* __restrict__ WB,
                    u16* __restrict__ A1)
{
  const int b = blockIdx.x;
  const int tid = threadIdx.x;
  if (b < W_BLOCKS) {
    const int g = b * 256 + tid;
    const int e = g * 4;
    const int S = 1024 * KDIM;
    float4 v;
    if (e < S)            v = *reinterpret_cast<const float4*>(Wr + e);
    else if (e < 2 * S)   v = *reinterpret_cast<const float4*>(Wz + (e - S));
    else                  v = *reinterpret_cast<const float4*>(Wh + (e - 2 * S));
    ushort4 o; o.x = f2bf(v.x); o.y = f2bf(v.y); o.z = f2bf(v.z); o.w = f2bf(v.w);
    *reinterpret_cast<ushort4*>(WB + e) = o;
  } else if (b < W_BLOCKS + H_BLOCKS) {
    const int g = (b - W_BLOCKS) * 256 + tid;
    const int e = g * 4;
    const int row = e >> 10, col = e & 1023;
    float4 v = *reinterpret_cast<const float4*>(h + e);
    ushort4 o; o.x = f2bf(v.x); o.y = f2bf(v.y); o.z = f2bf(v.z); o.w = f2bf(v.w);
    *reinterpret_cast<ushort4*>(A1 + (size_t)row * KDIM + IDIM + col) = o;
  } else {
    const int g = (b - W_BLOCKS - H_BLOCKS) * 256 + tid;
    const int e = g * 4;
    int ti = (int)t[0];
    ti = ti < 0 ? 0 : (ti > TMAX - 1 ? TMAX - 1 : ti);
    const int row = e >> 7, col = e & 127;
    float4 v = *reinterpret_cast<const float4*>(xc + (size_t)ti * B_ROWS * IDIM + e);
    ushort4 o; o.x = f2bf(v.x); o.y = f2bf(v.y); o.z = f2bf(v.z); o.w = f2bf(v.w);
    *reinterpret_cast<ushort4*>(A1 + (size_t)row * KDIM + col) = o;
  }
}

// ---------------------------------------------------------------------------
// GEMM1: 256x128 tile, BK=32, 3-slot ring (74 KB -> 2 blocks/CU), 4 waves of
// 128x64 -> 12 b128-reads per 32 MFMA (0.375 read/MFMA; per-CU LDS 1152 cyc <
// MFMA 1242 cyc -> MFMA-bound). R6 geometry MINUS sched_barrier (m141: the
// order-pin was the regression). bm-fastest XCD map (4 A-panels ~2.4 MB L2-
// resident). Counted vmcnt(6); grid 512 = 1 round.
// ---------------------------------------------------------------------------
__global__ __launch_bounds__(256, 2)
void gemm1_256(const u16* __restrict__ A, const u16* __restrict__ W,
               const u16* __restrict__ hb, u16* __restrict__ A2w,
               u16* __restrict__ omz)
{
  constexpr int NBN  = 2048 / 128;    // 16
  constexpr int BMPX = 32 / 8;        // 4 bm panels per XCD
  constexpr int NT   = KDIM / 32;     // 36 K-tiles

  __shared__ u16 As[3][256 * 32];
  __shared__ u16 Bs[3][128 * 32];

  const int tid  = threadIdx.x;
  const int lane = tid & 63;
  const int wave = tid >> 6;
  const int wm = wave >> 1, wn = wave & 1;          // 2x2 waves, tile 128x64
  const int xcd = blockIdx.x & 7, jj = blockIdx.x >> 3;
  const int bm = xcd * BMPX + (jj & (BMPX - 1));    // bm-fastest within XCD
  const int bn = jj / BMPX;
  const int rowBase = bm * 256, colBase = bn * 128;
  const int lr = lane & 15, lkq = lane >> 4;

  auto stage = [&](int slot, int kt) {
    #pragma unroll
    for (int rr = 0; rr < 4; ++rr) {                // A: 256x32 = 1024 chunks
      const int q = rr * 256 + tid;
      const int row = q >> 2, pc = q & 3;
      const int cg = pc ^ ((row >> 1) & 3);         // inverse-swizzled source
      const u16* g = A + (size_t)(rowBase + row) * KDIM + kt * 32 + cg * 8;
      __builtin_amdgcn_global_load_lds(
          (const __attribute__((address_space(1))) void*)g,
          (__attribute__((address_space(3))) void*)(&As[slot][q * 8]), 16, 0, 0);
    }
    #pragma unroll
    for (int rr = 0; rr < 2; ++rr) {                // B: 128x32 = 512 chunks
      const int q = rr * 256 + tid;
      const int row = q >> 2, pc = q & 3;
      const int cg = pc ^ ((row >> 1) & 3);
      const u16* g = W + (size_t)(colBase + row) * KDIM + kt * 32 + cg * 8;
      __builtin_amdgcn_global_load_lds(
          (const __attribute__((address_space(1))) void*)g,
          (__attribute__((address_space(3))) void*)(&Bs[slot][q * 8]), 16, 0, 0);
    }
  };

  f32x4 acc[8][4];
  f32x4 zero = {0.f, 0.f, 0.f, 0.f};
  #pragma unroll
  for (int i = 0; i < 8; ++i)
    #pragma unroll
    for (int j = 0; j < 4; ++j) acc[i][j] = zero;

#define PHASE1(T, DOSTAGE, WV)  do {                                            \
    if (DOSTAGE) stage((T + 2) % 3, (T) + 2);                                   \
    const int s_ = (T) % 3;                                                     \
    bf16x8 af[8], bv[4];                                                        \
    _Pragma("unroll") for (int mf = 0; mf < 8; ++mf) {                          \
      const int r = wm * 128 + mf * 16 + lr;                                    \
      const int c = lkq ^ ((r >> 1) & 3);                                       \
      af[mf] = *reinterpret_cast<const bf16x8*>(&As[s_][r * 32 + c * 8]);       \
    }                                                                           \
    _Pragma("unroll") for (int nf = 0; nf < 4; ++nf) {                          \
      const int r = wn * 64 + nf * 16 + lr;                                     \
      const int c = lkq ^ ((r >> 1) & 3);                                       \
      bv[nf] = *reinterpret_cast<const bf16x8*>(&Bs[s_][r * 32 + c * 8]);       \
    }                                                                           \
    __builtin_amdgcn_s_barrier();                                               \
    asm volatile("s_waitcnt lgkmcnt(0)" ::: "memory");                          \
    __builtin_amdgcn_s_setprio(1);                                              \
    _Pragma("unroll") for (int mf = 0; mf < 8; ++mf)                            \
      _Pragma("unroll") for (int nf = 0; nf < 4; ++nf)                          \
        acc[mf][nf] = __builtin_amdgcn_mfma_f32_16x16x32_bf16(                  \
            af[mf], bv[nf], acc[mf][nf], 0, 0, 0);                              \
    __builtin_amdgcn_s_setprio(0);                                              \
    waitv<WV>();                                                                \
    __builtin_amdgcn_s_barrier();                                               \
  } while (0)

  // Prologue: stage tiles 0,1; drain tile0 (6 of 12 loads), keep tile1 in flight.
  stage(0, 0); stage(1, 1);
  waitv<6>();
  __builtin_amdgcn_s_barrier();

  for (int t = 0; t < NT - 2; ++t) PHASE1(t, true, 6);
  PHASE1(NT - 2, false, 0);         // drain tile NT-1
  PHASE1(NT - 1, false, 0);
#undef PHASE1

  // ---- epilogue: C/D layout col=lr, row=lkq*4+rr ----
  if (colBase < HDIM) {                             // r-block: A2 = bf16(r*h)
    #pragma unroll
    for (int mf = 0; mf < 8; ++mf)
      #pragma unroll
      for (int nf = 0; nf < 4; ++nf) {
        f32x4 v = acc[mf][nf];
        const int col = colBase + wn * 64 + nf * 16 + lr;
        #pragma unroll
        for (int rr = 0; rr < 4; ++rr) {
          const int row = rowBase + wm * 128 + mf * 16 + lkq * 4 + rr;
          const float sg = 1.f / (1.f + __expf(-v[rr]));
          const float hv = bf2f(hb[(size_t)row * KDIM + IDIM + col]);
          A2w[(size_t)row * KDIM + IDIM + col] = f2bf(sg * hv);
        }
      }
  } else {                                          // z-block: omz = bf16(1-z)
    #pragma unroll
    for (int mf = 0; mf < 8; ++mf)
      #pragma unroll
      for (int nf = 0; nf < 4; ++nf) {
        f32x4 v = acc[mf][nf];
        const int col = colBase - HDIM + wn * 64 + nf * 16 + lr;
        #pragma unroll
        for (int rr = 0; rr < 4; ++rr) {
          const int row = rowBase + wm * 128 + mf * 16 + lkq * 4 + rr;
          const float sg = 1.f / (1.f + __expf(-v[rr]));
          omz[(size_t)row * HDIM + col] = f2bf(1.f - sg);
        }
      }
  }
}

// ---------------------------------------------------------------------------
// GEMM2: R8 gemm128 MODE 1 (proven). 128x128, 2-phase held-B, vmcnt(8),
// bm-fastest XCD map, x-cols sourced from A1.
// ---------------------------------------------------------------------------
__global__ __launch_bounds__(256, 2)
void gemm2_128(const u16* __restrict__ A, const u16* __restrict__ Ax,
               const u16* __restrict__ W,
               const u16* __restrict__ hb, const u16* __restrict__ omz,
               float* __restrict__ out)
{
  constexpr int NBN  = 1024 / 128;
  constexpr int BMPX = (B_ROWS / 128) / 8;
  constexpr int NT   = KDIM / 64;

  __shared__ u16 As[2][2][64 * 64];
  __shared__ u16 Bs[2][2][64 * 64];

  const int tid  = threadIdx.x;
  const int lane = tid & 63;
  const int wave = tid >> 6;
  const int wm = wave >> 1, wn = wave & 1;
  const int xcd = blockIdx.x & 7, jj = blockIdx.x >> 3;
  const int bm = xcd * BMPX + (jj & (BMPX - 1));
  const int bn = jj / BMPX;
  const int rowBase = bm * 128, colBase = bn * 128;
  const int lr = lane & 15, lkq = lane >> 4;

  auto stA = [&](int buf, int half, int kt) {
    const u16* src = (kt * 64 < IDIM) ? Ax : A;
    #pragma unroll
    for (int rr = 0; rr < 2; ++rr) {
      const int q = rr * 256 + tid;
      const int row = q >> 3, cl = q & 7;
      const int cg = cl ^ (row & 7);
      const u16* g = src + (size_t)(rowBase + half * 64 + row) * KDIM + kt * 64 + cg * 8;
      __builtin_amdgcn_global_load_lds(
          (const __attribute__((address_space(1))) void*)g,
          (__attribute__((address_space(3))) void*)(&As[buf][half][q * 8]), 16, 0, 0);
    }
  };
  auto stB = [&](int buf, int half, int kt) {
    #pragma unroll
    for (int rr = 0; rr < 2; ++rr) {
      const int q = rr * 256 + tid;
      const int row = q >> 3, cl = q & 7;
      const int cg = cl ^ (row & 7);
      const u16* g = W + (size_t)(colBase + half * 64 + row) * KDIM + kt * 64 + cg * 8;
      __builtin_amdgcn_global_load_lds(
          (const __attribute__((address_space(1))) void*)g,
          (__attribute__((address_space(3))) void*)(&Bs[buf][half][q * 8]), 16, 0, 0);
    }
  };

  f32x4 acc[2][2][2][2];
  f32x4 zero = {0.f, 0.f, 0.f, 0.f};
  #pragma unroll
  for (int a = 0; a < 2; ++a)
    #pragma unroll
    for (int b = 0; b < 2; ++b)
      #pragma unroll
      for (int c = 0; c < 2; ++c)
        #pragma unroll
        for (int d = 0; d < 2; ++d) acc[a][b][c][d] = zero;

  bf16x8 bv[2][2][2];
  bf16x8 af[2][2];

  auto rdA = [&](int buf, int half) {
    #pragma unroll
    for (int mf = 0; mf < 2; ++mf)
      #pragma unroll
      for (int kk = 0; kk < 2; ++kk) {
        const int r = wm * 32 + mf * 16 + lr;
        const int c = (kk * 4 + lkq) ^ (r & 7);
        af[mf][kk] = *reinterpret_cast<const bf16x8*>(&As[buf][half][r * 64 + c * 8]);
      }
  };
  auto rdB = [&](int buf) {
    #pragma unroll
    for (int nh = 0; nh < 2; ++nh)
      #pragma unroll
      for (int nf = 0; nf < 2; ++nf)
        #pragma unroll
        for (int kk = 0; kk < 2; ++kk) {
          const int r = wn * 32 + nf * 16 + lr;
          const int c = (kk * 4 + lkq) ^ (r & 7);
          bv[nh][nf][kk] = *reinterpret_cast<const bf16x8*>(&Bs[buf][nh][r * 64 + c * 8]);
        }
  };

#define MFMA_QUAD(MH, NH)                                                       \
    _Pragma("unroll") for (int mf = 0; mf < 2; ++mf)                            \
      _Pragma("unroll") for (int nf = 0; nf < 2; ++nf)                          \
        _Pragma("unroll") for (int kk = 0; kk < 2; ++kk)                        \
          acc[MH][NH][mf][nf] = __builtin_amdgcn_mfma_f32_16x16x32_bf16(        \
              af[mf][kk], bv[NH][nf][kk], acc[MH][NH][mf][nf], 0, 0, 0);

#define PHASE_A(BUF, T, DO_STAGE, WV)  do {                                     \
    rdA(BUF, 0); rdB(BUF);                                                      \
    if (DO_STAGE) stA((BUF) ^ 1, 1, (T) + 1);                                   \
    __builtin_amdgcn_s_barrier();                                               \
    asm volatile("s_waitcnt lgkmcnt(0)" ::: "memory");                          \
    __builtin_amdgcn_s_setprio(1);                                              \
    MFMA_QUAD(0, 0); MFMA_QUAD(0, 1);                                           \
    __builtin_amdgcn_s_setprio(0);                                              \
    waitv<WV>();                                                                \
    __builtin_amdgcn_s_barrier();                                               \
  } while (0)

#define PHASE_B(BUF, T, DO_STAGE, WV)  do {                                     \
    rdA(BUF, 1);                                                                \
    if (DO_STAGE) { stA(BUF, 0, (T) + 2); stB(BUF, 0, (T) + 2);                 \
                    stB(BUF, 1, (T) + 2); }                                     \
    __builtin_amdgcn_s_barrier();                                               \
    asm volatile("s_waitcnt lgkmcnt(0)" ::: "memory");                          \
    __builtin_amdgcn_s_setprio(1);                                              \
    MFMA_QUAD(1, 1); MFMA_QUAD(1, 0);                                           \
    __builtin_amdgcn_s_setprio(0);                                              \
    waitv<WV>();                                                                \
    __builtin_amdgcn_s_barrier();                                               \
  } while (0)

  stA(0, 0, 0); stB(0, 0, 0); stB(0, 1, 0); stA(0, 1, 0);
  stA(1, 0, 1); stB(1, 0, 1); stB(1, 1, 1);
  waitv<6>();
  __builtin_amdgcn_s_barrier();

  for (int t = 0; t < NT - 2; ++t) {
    const int buf = t & 1;
    PHASE_A(buf, t, true, 8);
    PHASE_B(buf, t, true, 8);
  }
  PHASE_A(0, 16, true, 8);
  PHASE_B(0, 16, false, 2);
  PHASE_A(1, 17, false, 0);
  PHASE_B(1, 17, false, 0);

#undef PHASE_A
#undef PHASE_B
#undef MFMA_QUAD

  #pragma unroll
  for (int mh = 0; mh < 2; ++mh)
    #pragma unroll
    for (int nh = 0; nh < 2; ++nh)
      #pragma unroll
      for (int mf = 0; mf < 2; ++mf)
        #pragma unroll
        for (int nf = 0; nf < 2; ++nf) {
          f32x4 v = acc[mh][nh][mf][nf];
          const int col = colBase + nh * 64 + wn * 32 + nf * 16 + lr;
          #pragma unroll
          for (int rr = 0; rr < 4; ++rr) {
            const int row = rowBase + mh * 64 + wm * 32 + mf * 16 + lkq * 4 + rr;
            const float e  = __expf(2.f * v[rr]);
            const float ht = 1.f - 2.f / (e + 1.f);
            const float o  = bf2f(omz[(size_t)row * HDIM + col]);
            const float hv = bf2f(hb[(size_t)row * KDIM + IDIM + col]);
            out[(size_t)row * HDIM + col] = o * (ht - hv);
          }
        }
}

// ---------------------------------------------------------------------------
extern "C" void kernel_launch(void* const* d_in, const int* in_sizes, int n_in,
                              void* d_out, int out_size, void* d_ws, size_t ws_size,
                              hipStream_t stream) {
  const float* t  = (const float*)d_in[0];
  const float* h  = (const float*)d_in[1];
  const float* xc = (const float*)d_in[2];
  const float* Wr = (const float*)d_in[3];
  const float* Wz = (const float*)d_in[4];
  const float* Wh = (const float*)d_in[5];
  float* out = (float*)d_out;

  u16* WB  = (u16*)d_ws;
  u16* A1  = WB + (size_t)3 * 1024 * KDIM;
  u16* A2  = A1 + (size_t)B_ROWS * KDIM;
  u16* omz = A2 + (size_t)B_ROWS * KDIM;

  convert_kernel<<<CV_BLOCKS, 256, 0, stream>>>(t, h, xc, Wr, Wz, Wh, WB, A1);

  // GEMM1: [x|h] x [W_r;W_z]^T -> r,z ; grid 32x16 = 512, 2 blocks/CU, 1 round
  gemm1_256<<<512, 256, 0, stream>>>(A1, WB, A1, A2, omz);

  // GEMM2: [x|r*h] x W_h^T -> out = (1-z)*(htilde - h) ; grid 64x8 = 512
  gemm2_128<<<512, 256, 0, stream>>>(A2, A1, WB + (size_t)2048 * KDIM,
                                     A1, omz, out);
}

// Round 10
// 87.623 us; speedup vs baseline: 1.0792x; 1.0792x over previous
//
#include <hip/hip_runtime.h>
#include <hip/hip_bf16.h>
#include <stdint.h>

#define B_ROWS 8192
#define HDIM   1024
#define IDIM   128
#define KDIM   1152
#define TMAX   128

typedef unsigned short u16;
typedef __bf16 bf16x8 __attribute__((ext_vector_type(8)));
typedef float  f32x4  __attribute__((ext_vector_type(4)));

static __device__ __forceinline__ u16 f2bf(float f) {
  union { float f; unsigned u; } v; v.f = f;
  unsigned r = v.u + 0x7FFFu + ((v.u >> 16) & 1u);
  return (u16)(r >> 16);
}
static __device__ __forceinline__ float bf2f(u16 b) {
  union { unsigned u; float f; } v; v.u = ((unsigned)b) << 16; return v.f;
}

template<int N> __device__ __forceinline__ void waitv() {
  if constexpr (N == 8)      asm volatile("s_waitcnt vmcnt(8)" ::: "memory");
  else if constexpr (N == 6) asm volatile("s_waitcnt vmcnt(6)" ::: "memory");
  else if constexpr (N == 2) asm volatile("s_waitcnt vmcnt(2)" ::: "memory");
  else                       asm volatile("s_waitcnt vmcnt(0)" ::: "memory");
}

// ---------------------------------------------------------------------------
// Kernel 1: bf16 conversion/staging (R8 version, verified)
// ---------------------------------------------------------------------------
#define W_CHUNKS  (3*1024*1152/4)
#define H_CHUNKS  (B_ROWS*HDIM/4)
#define X_CHUNKS  (B_ROWS*IDIM/4)
#define W_BLOCKS  (W_CHUNKS/256)
#define H_BLOCKS  (H_CHUNKS/256)
#define X_BLOCKS  (X_CHUNKS/256)
#define CV_BLOCKS (W_BLOCKS + H_BLOCKS + X_BLOCKS)

__global__ __launch_bounds__(256)
void convert_kernel(const float* __restrict__ t,
                    const float* __restrict__ h,
                    const float* __restrict__ xc,
                    const float* __restrict__ Wr,
                    const float* __restrict__ Wz,
                    const float* __restrict__ Wh,
                    u16* __restrict__ WB,
                    u16* __restrict__ A1)
{
  const int b = blockIdx.x;
  const int tid = threadIdx.x;
  if (b < W_BLOCKS) {
    const int g = b * 256 + tid;
    const int e = g * 4;
    const int S = 1024 * KDIM;
    float4 v;
    if (e < S)            v = *reinterpret_cast<const float4*>(Wr + e);
    else if (e < 2 * S)   v = *reinterpret_cast<const float4*>(Wz + (e - S));
    else                  v = *reinterpret_cast<const float4*>(Wh + (e - 2 * S));
    ushort4 o; o.x = f2bf(v.x); o.y = f2bf(v.y); o.z = f2bf(v.z); o.w = f2bf(v.w);
    *reinterpret_cast<ushort4*>(WB + e) = o;
  } else if (b < W_BLOCKS + H_BLOCKS) {
    const int g = (b - W_BLOCKS) * 256 + tid;
    const int e = g * 4;
    const int row = e >> 10, col = e & 1023;
    float4 v = *reinterpret_cast<const float4*>(h + e);
    ushort4 o; o.x = f2bf(v.x); o.y = f2bf(v.y); o.z = f2bf(v.z); o.w = f2bf(v.w);
    *reinterpret_cast<ushort4*>(A1 + (size_t)row * KDIM + IDIM + col) = o;
  } else {
    const int g = (b - W_BLOCKS - H_BLOCKS) * 256 + tid;
    const int e = g * 4;
    int ti = (int)t[0];
    ti = ti < 0 ? 0 : (ti > TMAX - 1 ? TMAX - 1 : ti);
    const int row = e >> 7, col = e & 127;
    float4 v = *reinterpret_cast<const float4*>(xc + (size_t)ti * B_ROWS * IDIM + e);
    ushort4 o; o.x = f2bf(v.x); o.y = f2bf(v.y); o.z = f2bf(v.z); o.w = f2bf(v.w);
    *reinterpret_cast<ushort4*>(A1 + (size_t)row * KDIM + col) = o;
  }
}

// ---------------------------------------------------------------------------
// GEMM1: 256x256 tile, BK=64 (128B rows -> full-cacheline DMA), dbuf 128 KB,
// 512 thr / 8 waves (2M x 4N, wave-tile 128x64). Staged bytes: 302 MB (half
// of R8's 590 MB) -- the supply-bound lever. Each wave reads ONLY its A-half
// (wm) and B-quarter (wn): 24 b128/wave/K-tile = minimum (per-CU LDS 2304 cyc
// < MFMA 2483 -> MFMA-bound if supply holds). ONE barrier per K-tile; tile
// t+1's 8 loads issued early in tile t (full-tile latency cover before the
// end-of-tile drain). bm-fastest XCD map: 4 A-panels + live B panel ~2.6 MB
// L2-resident. T2 chunk swizzle both sides; T5 setprio.
// ---------------------------------------------------------------------------
__global__ __launch_bounds__(512, 2)
void gemm1_256sq(const u16* __restrict__ A, const u16* __restrict__ W,
                 const u16* __restrict__ hb, u16* __restrict__ A2w,
                 u16* __restrict__ omz)
{
  constexpr int NBN  = 2048 / 256;   // 8
  constexpr int BMPX = 32 / 8;       // 4 bm panels per XCD
  constexpr int NT   = KDIM / 64;    // 18 K-tiles

  __shared__ u16 As[2][256 * 64];
  __shared__ u16 Bs[2][256 * 64];

  const int tid  = threadIdx.x;
  const int lane = tid & 63;
  const int wave = tid >> 6;
  const int wm = wave >> 2, wn = wave & 3;          // wave-tile 128x64
  const int xcd = blockIdx.x & 7, jj = blockIdx.x >> 3;   // grid 256
  const int bm = xcd * BMPX + (jj & (BMPX - 1));    // bm-fastest within XCD
  const int bn = jj >> 2;                           // 0..7
  const int rowBase = bm * 256, colBase = bn * 256;
  const int lr = lane & 15, lkq = lane >> 4;

  auto stage = [&](int buf, int kt) {
    #pragma unroll
    for (int rr = 0; rr < 4; ++rr) {                // A: 256x64 = 2048 chunks
      const int q = rr * 512 + tid;
      const int row = q >> 3, cl = q & 7;
      const int cg = cl ^ (row & 7);                // inverse-swizzled source
      const u16* g = A + (size_t)(rowBase + row) * KDIM + kt * 64 + cg * 8;
      __builtin_amdgcn_global_load_lds(
          (const __attribute__((address_space(1))) void*)g,
          (__attribute__((address_space(3))) void*)(&As[buf][q * 8]), 16, 0, 0);
    }
    #pragma unroll
    for (int rr = 0; rr < 4; ++rr) {                // B: 256x64 = 2048 chunks
      const int q = rr * 512 + tid;
      const int row = q >> 3, cl = q & 7;
      const int cg = cl ^ (row & 7);
      const u16* g = W + (size_t)(colBase + row) * KDIM + kt * 64 + cg * 8;
      __builtin_amdgcn_global_load_lds(
          (const __attribute__((address_space(1))) void*)g,
          (__attribute__((address_space(3))) void*)(&Bs[buf][q * 8]), 16, 0, 0);
    }
  };

  f32x4 acc[8][4];
  f32x4 zero = {0.f, 0.f, 0.f, 0.f};
  #pragma unroll
  for (int i = 0; i < 8; ++i)
    #pragma unroll
    for (int j = 0; j < 4; ++j) acc[i][j] = zero;

  // Prologue: stage tile 0 only; drain; barrier.
  stage(0, 0);
  waitv<0>();
  __builtin_amdgcn_s_barrier();

  for (int t = 0; t < NT; ++t) {
    const int buf = t & 1;
    // ---- k-half 0: 12 ds_reads ----
    bf16x8 af[8], bv[4];
    #pragma unroll
    for (int mf = 0; mf < 8; ++mf) {
      const int r = wm * 128 + mf * 16 + lr;
      const int c = lkq ^ (r & 7);
      af[mf] = *reinterpret_cast<const bf16x8*>(&As[buf][r * 64 + c * 8]);
    }
    #pragma unroll
    for (int nf = 0; nf < 4; ++nf) {
      const int r = wn * 64 + nf * 16 + lr;
      const int c = lkq ^ (r & 7);
      bv[nf] = *reinterpret_cast<const bf16x8*>(&Bs[buf][r * 64 + c * 8]);
    }
    // issue next tile's 8 DMA loads (land by end of this tile ~1 us away)
    if (t + 1 < NT) stage(buf ^ 1, t + 1);
    asm volatile("s_waitcnt lgkmcnt(0)" ::: "memory");
    __builtin_amdgcn_s_setprio(1);
    #pragma unroll
    for (int mf = 0; mf < 8; ++mf)
      #pragma unroll
      for (int nf = 0; nf < 4; ++nf)
        acc[mf][nf] = __builtin_amdgcn_mfma_f32_16x16x32_bf16(
            af[mf], bv[nf], acc[mf][nf], 0, 0, 0);
    __builtin_amdgcn_s_setprio(0);
    // ---- k-half 1 ----
    #pragma unroll
    for (int mf = 0; mf < 8; ++mf) {
      const int r = wm * 128 + mf * 16 + lr;
      const int c = (4 + lkq) ^ (r & 7);
      af[mf] = *reinterpret_cast<const bf16x8*>(&As[buf][r * 64 + c * 8]);
    }
    #pragma unroll
    for (int nf = 0; nf < 4; ++nf) {
      const int r = wn * 64 + nf * 16 + lr;
      const int c = (4 + lkq) ^ (r & 7);
      bv[nf] = *reinterpret_cast<const bf16x8*>(&Bs[buf][r * 64 + c * 8]);
    }
    asm volatile("s_waitcnt lgkmcnt(0)" ::: "memory");
    __builtin_amdgcn_s_setprio(1);
    #pragma unroll
    for (int mf = 0; mf < 8; ++mf)
      #pragma unroll
      for (int nf = 0; nf < 4; ++nf)
        acc[mf][nf] = __builtin_amdgcn_mfma_f32_16x16x32_bf16(
            af[mf], bv[nf], acc[mf][nf], 0, 0, 0);
    __builtin_amdgcn_s_setprio(0);
    // next tile fully landed + all waves' reads done -> safe to flip buffers
    waitv<0>();
    __builtin_amdgcn_s_barrier();
  }

  // ---- epilogue: C/D layout col=lr, row=lkq*4+rr ----
  if (colBase < HDIM) {                             // r-block: A2 = bf16(r*h)
    #pragma unroll
    for (int mf = 0; mf < 8; ++mf)
      #pragma unroll
      for (int nf = 0; nf < 4; ++nf) {
        f32x4 v = acc[mf][nf];
        const int col = colBase + wn * 64 + nf * 16 + lr;
        #pragma unroll
        for (int rr = 0; rr < 4; ++rr) {
          const int row = rowBase + wm * 128 + mf * 16 + lkq * 4 + rr;
          const float sg = 1.f / (1.f + __expf(-v[rr]));
          const float hv = bf2f(hb[(size_t)row * KDIM + IDIM + col]);
          A2w[(size_t)row * KDIM + IDIM + col] = f2bf(sg * hv);
        }
      }
  } else {                                          // z-block: omz = bf16(1-z)
    #pragma unroll
    for (int mf = 0; mf < 8; ++mf)
      #pragma unroll
      for (int nf = 0; nf < 4; ++nf) {
        f32x4 v = acc[mf][nf];
        const int col = colBase - HDIM + wn * 64 + nf * 16 + lr;
        #pragma unroll
        for (int rr = 0; rr < 4; ++rr) {
          const int row = rowBase + wm * 128 + mf * 16 + lkq * 4 + rr;
          const float sg = 1.f / (1.f + __expf(-v[rr]));
          omz[(size_t)row * HDIM + col] = f2bf(1.f - sg);
        }
      }
  }
}

// ---------------------------------------------------------------------------
// GEMM2: R8 gemm128 MODE 1 (proven). 128x128, 2-phase held-B, vmcnt(8),
// bm-fastest XCD map, x-cols sourced from A1.
// ---------------------------------------------------------------------------
__global__ __launch_bounds__(256, 2)
void gemm2_128(const u16* __restrict__ A, const u16* __restrict__ Ax,
               const u16* __restrict__ W,
               const u16* __restrict__ hb, const u16* __restrict__ omz,
               float* __restrict__ out)
{
  constexpr int NBN  = 1024 / 128;
  constexpr int BMPX = (B_ROWS / 128) / 8;
  constexpr int NT   = KDIM / 64;

  __shared__ u16 As[2][2][64 * 64];
  __shared__ u16 Bs[2][2][64 * 64];

  const int tid  = threadIdx.x;
  const int lane = tid & 63;
  const int wave = tid >> 6;
  const int wm = wave >> 1, wn = wave & 1;
  const int xcd = blockIdx.x & 7, jj = blockIdx.x >> 3;
  const int bm = xcd * BMPX + (jj & (BMPX - 1));
  const int bn = jj / BMPX;
  const int rowBase = bm * 128, colBase = bn * 128;
  const int lr = lane & 15, lkq = lane >> 4;

  auto stA = [&](int buf, int half, int kt) {
    const u16* src = (kt * 64 < IDIM) ? Ax : A;
    #pragma unroll
    for (int rr = 0; rr < 2; ++rr) {
      const int q = rr * 256 + tid;
      const int row = q >> 3, cl = q & 7;
      const int cg = cl ^ (row & 7);
      const u16* g = src + (size_t)(rowBase + half * 64 + row) * KDIM + kt * 64 + cg * 8;
      __builtin_amdgcn_global_load_lds(
          (const __attribute__((address_space(1))) void*)g,
          (__attribute__((address_space(3))) void*)(&As[buf][half][q * 8]), 16, 0, 0);
    }
  };
  auto stB = [&](int buf, int half, int kt) {
    #pragma unroll
    for (int rr = 0; rr < 2; ++rr) {
      const int q = rr * 256 + tid;
      const int row = q >> 3, cl = q & 7;
      const int cg = cl ^ (row & 7);
      const u16* g = W + (size_t)(colBase + half * 64 + row) * KDIM + kt * 64 + cg * 8;
      __builtin_amdgcn_global_load_lds(
          (const __attribute__((address_space(1))) void*)g,
          (__attribute__((address_space(3))) void*)(&Bs[buf][half][q * 8]), 16, 0, 0);
    }
  };

  f32x4 acc[2][2][2][2];
  f32x4 zero = {0.f, 0.f, 0.f, 0.f};
  #pragma unroll
  for (int a = 0; a < 2; ++a)
    #pragma unroll
    for (int b = 0; b < 2; ++b)
      #pragma unroll
      for (int c = 0; c < 2; ++c)
        #pragma unroll
        for (int d = 0; d < 2; ++d) acc[a][b][c][d] = zero;

  bf16x8 bv[2][2][2];
  bf16x8 af[2][2];

  auto rdA = [&](int buf, int half) {
    #pragma unroll
    for (int mf = 0; mf < 2; ++mf)
      #pragma unroll
      for (int kk = 0; kk < 2; ++kk) {
        const int r = wm * 32 + mf * 16 + lr;
        const int c = (kk * 4 + lkq) ^ (r & 7);
        af[mf][kk] = *reinterpret_cast<const bf16x8*>(&As[buf][half][r * 64 + c * 8]);
      }
  };
  auto rdB = [&](int buf) {
    #pragma unroll
    for (int nh = 0; nh < 2; ++nh)
      #pragma unroll
      for (int nf = 0; nf < 2; ++nf)
        #pragma unroll
        for (int kk = 0; kk < 2; ++kk) {
          const int r = wn * 32 + nf * 16 + lr;
          const int c = (kk * 4 + lkq) ^ (r & 7);
          bv[nh][nf][kk] = *reinterpret_cast<const bf16x8*>(&Bs[buf][nh][r * 64 + c * 8]);
        }
  };

#define MFMA_QUAD(MH, NH)                                                       \
    _Pragma("unroll") for (int mf = 0; mf < 2; ++mf)                            \
      _Pragma("unroll") for (int nf = 0; nf < 2; ++nf)                          \
        _Pragma("unroll") for (int kk = 0; kk < 2; ++kk)                        \
          acc[MH][NH][mf][nf] = __builtin_amdgcn_mfma_f32_16x16x32_bf16(        \
              af[mf][kk], bv[NH][nf][kk], acc[MH][NH][mf][nf], 0, 0, 0);

#define PHASE_A(BUF, T, DO_STAGE, WV)  do {                                     \
    rdA(BUF, 0); rdB(BUF);                                                      \
    if (DO_STAGE) stA((BUF) ^ 1, 1, (T) + 1);                                   \
    __builtin_amdgcn_s_barrier();                                               \
    asm volatile("s_waitcnt lgkmcnt(0)" ::: "memory");                          \
    __builtin_amdgcn_s_setprio(1);                                              \
    MFMA_QUAD(0, 0); MFMA_QUAD(0, 1);                                           \
    __builtin_amdgcn_s_setprio(0);                                              \
    waitv<WV>();                                                                \
    __builtin_amdgcn_s_barrier();                                               \
  } while (0)

#define PHASE_B(BUF, T, DO_STAGE, WV)  do {                                     \
    rdA(BUF, 1);                                                                \
    if (DO_STAGE) { stA(BUF, 0, (T) + 2); stB(BUF, 0, (T) + 2);                 \
                    stB(BUF, 1, (T) + 2); }                                     \
    __builtin_amdgcn_s_barrier();                                               \
    asm volatile("s_waitcnt lgkmcnt(0)" ::: "memory");                          \
    __builtin_amdgcn_s_setprio(1);                                              \
    MFMA_QUAD(1, 1); MFMA_QUAD(1, 0);                                           \
    __builtin_amdgcn_s_setprio(0);                                              \
    waitv<WV>();                                                                \
    __builtin_amdgcn_s_barrier();                                               \
  } while (0)

  stA(0, 0, 0); stB(0, 0, 0); stB(0, 1, 0); stA(0, 1, 0);
  stA(1, 0, 1); stB(1, 0, 1); stB(1, 1, 1);
  waitv<6>();
  __builtin_amdgcn_s_barrier();

  for (int t = 0; t < NT - 2; ++t) {
    const int buf = t & 1;
    PHASE_A(buf, t, true, 8);
    PHASE_B(buf, t, true, 8);
  }
  PHASE_A(0, 16, true, 8);
  PHASE_B(0, 16, false, 2);
  PHASE_A(1, 17, false, 0);
  PHASE_B(1, 17, false, 0);

#undef PHASE_A
#undef PHASE_B
#undef MFMA_QUAD

  #pragma unroll
  for (int mh = 0; mh < 2; ++mh)
    #pragma unroll
    for (int nh = 0; nh < 2; ++nh)
      #pragma unroll
      for (int mf = 0; mf < 2; ++mf)
        #pragma unroll
        for (int nf = 0; nf < 2; ++nf) {
          f32x4 v = acc[mh][nh][mf][nf];
          const int col = colBase + nh * 64 + wn * 32 + nf * 16 + lr;
          #pragma unroll
          for (int rr = 0; rr < 4; ++rr) {
            const int row = rowBase + mh * 64 + wm * 32 + mf * 16 + lkq * 4 + rr;
            const float e  = __expf(2.f * v[rr]);
            const float ht = 1.f - 2.f / (e + 1.f);
            const float o  = bf2f(omz[(size_t)row * HDIM + col]);
            const float hv = bf2f(hb[(size_t)row * KDIM + IDIM + col]);
            out[(size_t)row * HDIM + col] = o * (ht - hv);
          }
        }
}

// ---------------------------------------------------------------------------
extern "C" void kernel_launch(void* const* d_in, const int* in_sizes, int n_in,
                              void* d_out, int out_size, void* d_ws, size_t ws_size,
                              hipStream_t stream) {
  const float* t  = (const float*)d_in[0];
  const float* h  = (const float*)d_in[1];
  const float* xc = (const float*)d_in[2];
  const float* Wr = (const float*)d_in[3];
  const float* Wz = (const float*)d_in[4];
  const float* Wh = (const float*)d_in[5];
  float* out = (float*)d_out;

  u16* WB  = (u16*)d_ws;
  u16* A1  = WB + (size_t)3 * 1024 * KDIM;
  u16* A2  = A1 + (size_t)B_ROWS * KDIM;
  u16* omz = A2 + (size_t)B_ROWS * KDIM;

  convert_kernel<<<CV_BLOCKS, 256, 0, stream>>>(t, h, xc, Wr, Wz, Wh, WB, A1);

  // GEMM1: [x|h] x [W_r;W_z]^T -> r,z ; 256x256 tiles, grid 32x8 = 256, 1/CU
  gemm1_256sq<<<256, 512, 0, stream>>>(A1, WB, A1, A2, omz);

  // GEMM2: [x|r*h] x W_h^T -> out = (1-z)*(htilde - h) ; grid 64x8 = 512
  gemm2_128<<<512, 256, 0, stream>>>(A2, A1, WB + (size_t)2048 * KDIM,
                                     A1, omz, out);
}

// Round 11
// 87.611 us; speedup vs baseline: 1.0794x; 1.0001x over previous
//
#include <hip/hip_runtime.h>
#include <hip/hip_bf16.h>
#include <stdint.h>

#define B_ROWS 8192
#define HDIM   1024
#define IDIM   128
#define KDIM   1152
#define TMAX   128

typedef unsigned short u16;
typedef __bf16 bf16x8 __attribute__((ext_vector_type(8)));
typedef float  f32x4  __attribute__((ext_vector_type(4)));

static __device__ __forceinline__ u16 f2bf(float f) {
  union { float f; unsigned u; } v; v.f = f;
  unsigned r = v.u + 0x7FFFu + ((v.u >> 16) & 1u);
  return (u16)(r >> 16);
}
static __device__ __forceinline__ float bf2f(u16 b) {
  union { unsigned u; float f; } v; v.u = ((unsigned)b) << 16; return v.f;
}

template<int N> __device__ __forceinline__ void waitv() {
  if constexpr (N == 8)      asm volatile("s_waitcnt vmcnt(8)" ::: "memory");
  else if constexpr (N == 6) asm volatile("s_waitcnt vmcnt(6)" ::: "memory");
  else if constexpr (N == 2) asm volatile("s_waitcnt vmcnt(2)" ::: "memory");
  else                       asm volatile("s_waitcnt vmcnt(0)" ::: "memory");
}

// ---------------------------------------------------------------------------
// Kernel 1: bf16 conversion/staging (R8 version, verified)
// ---------------------------------------------------------------------------
#define W_CHUNKS  (3*1024*1152/4)
#define H_CHUNKS  (B_ROWS*HDIM/4)
#define X_CHUNKS  (B_ROWS*IDIM/4)
#define W_BLOCKS  (W_CHUNKS/256)
#define H_BLOCKS  (H_CHUNKS/256)
#define X_BLOCKS  (X_CHUNKS/256)
#define CV_BLOCKS (W_BLOCKS + H_BLOCKS + X_BLOCKS)

__global__ __launch_bounds__(256)
void convert_kernel(const float* __restrict__ t,
                    const float* __restrict__ h,
                    const float* __restrict__ xc,
                    const float* __restrict__ Wr,
                    const float* __restrict__ Wz,
                    const float* __restrict__ Wh,
                    u16* __restrict__ WB,
                    u16* __restrict__ A1)
{
  const int b = blockIdx.x;
  const int tid = threadIdx.x;
  if (b < W_BLOCKS) {
    const int g = b * 256 + tid;
    const int e = g * 4;
    const int S = 1024 * KDIM;
    float4 v;
    if (e < S)            v = *reinterpret_cast<const float4*>(Wr + e);
    else if (e < 2 * S)   v = *reinterpret_cast<const float4*>(Wz + (e - S));
    else                  v = *reinterpret_cast<const float4*>(Wh + (e - 2 * S));
    ushort4 o; o.x = f2bf(v.x); o.y = f2bf(v.y); o.z = f2bf(v.z); o.w = f2bf(v.w);
    *reinterpret_cast<ushort4*>(WB + e) = o;
  } else if (b < W_BLOCKS + H_BLOCKS) {
    const int g = (b - W_BLOCKS) * 256 + tid;
    const int e = g * 4;
    const int row = e >> 10, col = e & 1023;
    float4 v = *reinterpret_cast<const float4*>(h + e);
    ushort4 o; o.x = f2bf(v.x); o.y = f2bf(v.y); o.z = f2bf(v.z); o.w = f2bf(v.w);
    *reinterpret_cast<ushort4*>(A1 + (size_t)row * KDIM + IDIM + col) = o;
  } else {
    const int g = (b - W_BLOCKS - H_BLOCKS) * 256 + tid;
    const int e = g * 4;
    int ti = (int)t[0];
    ti = ti < 0 ? 0 : (ti > TMAX - 1 ? TMAX - 1 : ti);
    const int row = e >> 7, col = e & 127;
    float4 v = *reinterpret_cast<const float4*>(xc + (size_t)ti * B_ROWS * IDIM + e);
    ushort4 o; o.x = f2bf(v.x); o.y = f2bf(v.y); o.z = f2bf(v.z); o.w = f2bf(v.w);
    *reinterpret_cast<ushort4*>(A1 + (size_t)row * KDIM + col) = o;
  }
}

// ---------------------------------------------------------------------------
// GEMM1: 256x256 tile, BK=64, dbuf 128 KB, 512 thr / 8 waves (2M x 4N,
// wave-tile 128x64). R10 structure EXCEPT launch_bounds: (512,2) requested
// 2 waves/EU -> 128-VGPR cap, but acc[8][4] f32x4 ALONE is 128 VGPR ->
// accumulator spilled to scratch every tile. (512) caps at 256 VGPR (the
// block is 1/CU anyway at 128 KB LDS) -> no spill.
// ---------------------------------------------------------------------------
__global__ __launch_bounds__(512)
void gemm1_256sq(const u16* __restrict__ A, const u16* __restrict__ W,
                 const u16* __restrict__ hb, u16* __restrict__ A2w,
                 u16* __restrict__ omz)
{
  constexpr int BMPX = 32 / 8;       // 4 bm panels per XCD
  constexpr int NT   = KDIM / 64;    // 18 K-tiles

  __shared__ u16 As[2][256 * 64];
  __shared__ u16 Bs[2][256 * 64];

  const int tid  = threadIdx.x;
  const int lane = tid & 63;
  const int wave = tid >> 6;
  const int wm = wave >> 2, wn = wave & 3;          // wave-tile 128x64
  const int xcd = blockIdx.x & 7, jj = blockIdx.x >> 3;   // grid 256
  const int bm = xcd * BMPX + (jj & (BMPX - 1));    // bm-fastest within XCD
  const int bn = jj >> 2;                           // 0..7
  const int rowBase = bm * 256, colBase = bn * 256;
  const int lr = lane & 15, lkq = lane >> 4;

  auto stage = [&](int buf, int kt) {
    #pragma unroll
    for (int rr = 0; rr < 4; ++rr) {                // A: 256x64 = 2048 chunks
      const int q = rr * 512 + tid;
      const int row = q >> 3, cl = q & 7;
      const int cg = cl ^ (row & 7);                // inverse-swizzled source
      const u16* g = A + (size_t)(rowBase + row) * KDIM + kt * 64 + cg * 8;
      __builtin_amdgcn_global_load_lds(
          (const __attribute__((address_space(1))) void*)g,
          (__attribute__((address_space(3))) void*)(&As[buf][q * 8]), 16, 0, 0);
    }
    #pragma unroll
    for (int rr = 0; rr < 4; ++rr) {                // B: 256x64 = 2048 chunks
      const int q = rr * 512 + tid;
      const int row = q >> 3, cl = q & 7;
      const int cg = cl ^ (row & 7);
      const u16* g = W + (size_t)(colBase + row) * KDIM + kt * 64 + cg * 8;
      __builtin_amdgcn_global_load_lds(
          (const __attribute__((address_space(1))) void*)g,
          (__attribute__((address_space(3))) void*)(&Bs[buf][q * 8]), 16, 0, 0);
    }
  };

  f32x4 acc[8][4];
  f32x4 zero = {0.f, 0.f, 0.f, 0.f};
  #pragma unroll
  for (int i = 0; i < 8; ++i)
    #pragma unroll
    for (int j = 0; j < 4; ++j) acc[i][j] = zero;

  // Prologue: stage tile 0 only; drain; barrier.
  stage(0, 0);
  waitv<0>();
  __builtin_amdgcn_s_barrier();

  for (int t = 0; t < NT; ++t) {
    const int buf = t & 1;
    // ---- k-half 0: 12 ds_reads ----
    bf16x8 af[8], bv[4];
    #pragma unroll
    for (int mf = 0; mf < 8; ++mf) {
      const int r = wm * 128 + mf * 16 + lr;
      const int c = lkq ^ (r & 7);
      af[mf] = *reinterpret_cast<const bf16x8*>(&As[buf][r * 64 + c * 8]);
    }
    #pragma unroll
    for (int nf = 0; nf < 4; ++nf) {
      const int r = wn * 64 + nf * 16 + lr;
      const int c = lkq ^ (r & 7);
      bv[nf] = *reinterpret_cast<const bf16x8*>(&Bs[buf][r * 64 + c * 8]);
    }
    // issue next tile's 8 DMA loads (land by end of this tile)
    if (t + 1 < NT) stage(buf ^ 1, t + 1);
    asm volatile("s_waitcnt lgkmcnt(0)" ::: "memory");
    __builtin_amdgcn_s_setprio(1);
    #pragma unroll
    for (int mf = 0; mf < 8; ++mf)
      #pragma unroll
      for (int nf = 0; nf < 4; ++nf)
        acc[mf][nf] = __builtin_amdgcn_mfma_f32_16x16x32_bf16(
            af[mf], bv[nf], acc[mf][nf], 0, 0, 0);
    __builtin_amdgcn_s_setprio(0);
    // ---- k-half 1 ----
    #pragma unroll
    for (int mf = 0; mf < 8; ++mf) {
      const int r = wm * 128 + mf * 16 + lr;
      const int c = (4 + lkq) ^ (r & 7);
      af[mf] = *reinterpret_cast<const bf16x8*>(&As[buf][r * 64 + c * 8]);
    }
    #pragma unroll
    for (int nf = 0; nf < 4; ++nf) {
      const int r = wn * 64 + nf * 16 + lr;
      const int c = (4 + lkq) ^ (r & 7);
      bv[nf] = *reinterpret_cast<const bf16x8*>(&Bs[buf][r * 64 + c * 8]);
    }
    asm volatile("s_waitcnt lgkmcnt(0)" ::: "memory");
    __builtin_amdgcn_s_setprio(1);
    #pragma unroll
    for (int mf = 0; mf < 8; ++mf)
      #pragma unroll
      for (int nf = 0; nf < 4; ++nf)
        acc[mf][nf] = __builtin_amdgcn_mfma_f32_16x16x32_bf16(
            af[mf], bv[nf], acc[mf][nf], 0, 0, 0);
    __builtin_amdgcn_s_setprio(0);
    // next tile fully landed + all waves' reads done -> safe to flip buffers
    waitv<0>();
    __builtin_amdgcn_s_barrier();
  }

  // ---- epilogue: C/D layout col=lr, row=lkq*4+rr ----
  if (colBase < HDIM) {                             // r-block: A2 = bf16(r*h)
    #pragma unroll
    for (int mf = 0; mf < 8; ++mf)
      #pragma unroll
      for (int nf = 0; nf < 4; ++nf) {
        f32x4 v = acc[mf][nf];
        const int col = colBase + wn * 64 + nf * 16 + lr;
        #pragma unroll
        for (int rr = 0; rr < 4; ++rr) {
          const int row = rowBase + wm * 128 + mf * 16 + lkq * 4 + rr;
          const float sg = 1.f / (1.f + __expf(-v[rr]));
          const float hv = bf2f(hb[(size_t)row * KDIM + IDIM + col]);
          A2w[(size_t)row * KDIM + IDIM + col] = f2bf(sg * hv);
        }
      }
  } else {                                          // z-block: omz = bf16(1-z)
    #pragma unroll
    for (int mf = 0; mf < 8; ++mf)
      #pragma unroll
      for (int nf = 0; nf < 4; ++nf) {
        f32x4 v = acc[mf][nf];
        const int col = colBase - HDIM + wn * 64 + nf * 16 + lr;
        #pragma unroll
        for (int rr = 0; rr < 4; ++rr) {
          const int row = rowBase + wm * 128 + mf * 16 + lkq * 4 + rr;
          const float sg = 1.f / (1.f + __expf(-v[rr]));
          omz[(size_t)row * HDIM + col] = f2bf(1.f - sg);
        }
      }
  }
}

// ---------------------------------------------------------------------------
// GEMM2: R8 gemm128 MODE 1 (proven). 128x128, 2-phase held-B, vmcnt(8),
// bm-fastest XCD map, x-cols sourced from A1.  Unchanged.
// ---------------------------------------------------------------------------
__global__ __launch_bounds__(256, 2)
void gemm2_128(const u16* __restrict__ A, const u16* __restrict__ Ax,
               const u16* __restrict__ W,
               const u16* __restrict__ hb, const u16* __restrict__ omz,
               float* __restrict__ out)
{
  constexpr int NBN  = 1024 / 128;
  constexpr int BMPX = (B_ROWS / 128) / 8;
  constexpr int NT   = KDIM / 64;

  __shared__ u16 As[2][2][64 * 64];
  __shared__ u16 Bs[2][2][64 * 64];

  const int tid  = threadIdx.x;
  const int lane = tid & 63;
  const int wave = tid >> 6;
  const int wm = wave >> 1, wn = wave & 1;
  const int xcd = blockIdx.x & 7, jj = blockIdx.x >> 3;
  const int bm = xcd * BMPX + (jj & (BMPX - 1));
  const int bn = jj / BMPX;
  const int rowBase = bm * 128, colBase = bn * 128;
  const int lr = lane & 15, lkq = lane >> 4;

  auto stA = [&](int buf, int half, int kt) {
    const u16* src = (kt * 64 < IDIM) ? Ax : A;
    #pragma unroll
    for (int rr = 0; rr < 2; ++rr) {
      const int q = rr * 256 + tid;
      const int row = q >> 3, cl = q & 7;
      const int cg = cl ^ (row & 7);
      const u16* g = src + (size_t)(rowBase + half * 64 + row) * KDIM + kt * 64 + cg * 8;
      __builtin_amdgcn_global_load_lds(
          (const __attribute__((address_space(1))) void*)g,
          (__attribute__((address_space(3))) void*)(&As[buf][half][q * 8]), 16, 0, 0);
    }
  };
  auto stB = [&](int buf, int half, int kt) {
    #pragma unroll
    for (int rr = 0; rr < 2; ++rr) {
      const int q = rr * 256 + tid;
      const int row = q >> 3, cl = q & 7;
      const int cg = cl ^ (row & 7);
      const u16* g = W + (size_t)(colBase + half * 64 + row) * KDIM + kt * 64 + cg * 8;
      __builtin_amdgcn_global_load_lds(
          (const __attribute__((address_space(1))) void*)g,
          (__attribute__((address_space(3))) void*)(&Bs[buf][half][q * 8]), 16, 0, 0);
    }
  };

  f32x4 acc[2][2][2][2];
  f32x4 zero = {0.f, 0.f, 0.f, 0.f};
  #pragma unroll
  for (int a = 0; a < 2; ++a)
    #pragma unroll
    for (int b = 0; b < 2; ++b)
      #pragma unroll
      for (int c = 0; c < 2; ++c)
        #pragma unroll
        for (int d = 0; d < 2; ++d) acc[a][b][c][d] = zero;

  bf16x8 bv[2][2][2];
  bf16x8 af[2][2];

  auto rdA = [&](int buf, int half) {
    #pragma unroll
    for (int mf = 0; mf < 2; ++mf)
      #pragma unroll
      for (int kk = 0; kk < 2; ++kk) {
        const int r = wm * 32 + mf * 16 + lr;
        const int c = (kk * 4 + lkq) ^ (r & 7);
        af[mf][kk] = *reinterpret_cast<const bf16x8*>(&As[buf][half][r * 64 + c * 8]);
      }
  };
  auto rdB = [&](int buf) {
    #pragma unroll
    for (int nh = 0; nh < 2; ++nh)
      #pragma unroll
      for (int nf = 0; nf < 2; ++nf)
        #pragma unroll
        for (int kk = 0; kk < 2; ++kk) {
          const int r = wn * 32 + nf * 16 + lr;
          const int c = (kk * 4 + lkq) ^ (r & 7);
          bv[nh][nf][kk] = *reinterpret_cast<const bf16x8*>(&Bs[buf][nh][r * 64 + c * 8]);
        }
  };

#define MFMA_QUAD(MH, NH)                                                       \
    _Pragma("unroll") for (int mf = 0; mf < 2; ++mf)                            \
      _Pragma("unroll") for (int nf = 0; nf < 2; ++nf)                          \
        _Pragma("unroll") for (int kk = 0; kk < 2; ++kk)                        \
          acc[MH][NH][mf][nf] = __builtin_amdgcn_mfma_f32_16x16x32_bf16(        \
              af[mf][kk], bv[NH][nf][kk], acc[MH][NH][mf][nf], 0, 0, 0);

#define PHASE_A(BUF, T, DO_STAGE, WV)  do {                                     \
    rdA(BUF, 0); rdB(BUF);                                                      \
    if (DO_STAGE) stA((BUF) ^ 1, 1, (T) + 1);                                   \
    __builtin_amdgcn_s_barrier();                                               \
    asm volatile("s_waitcnt lgkmcnt(0)" ::: "memory");                          \
    __builtin_amdgcn_s_setprio(1);                                              \
    MFMA_QUAD(0, 0); MFMA_QUAD(0, 1);                                           \
    __builtin_amdgcn_s_setprio(0);                                              \
    waitv<WV>();                                                                \
    __builtin_amdgcn_s_barrier();                                               \
  } while (0)

#define PHASE_B(BUF, T, DO_STAGE, WV)  do {                                     \
    rdA(BUF, 1);                                                                \
    if (DO_STAGE) { stA(BUF, 0, (T) + 2); stB(BUF, 0, (T) + 2);                 \
                    stB(BUF, 1, (T) + 2); }                                     \
    __builtin_amdgcn_s_barrier();                                               \
    asm volatile("s_waitcnt lgkmcnt(0)" ::: "memory");                          \
    __builtin_amdgcn_s_setprio(1);                                              \
    MFMA_QUAD(1, 1); MFMA_QUAD(1, 0);                                           \
    __builtin_amdgcn_s_setprio(0);                                              \
    waitv<WV>();                                                                \
    __builtin_amdgcn_s_barrier();                                               \
  } while (0)

  stA(0, 0, 0); stB(0, 0, 0); stB(0, 1, 0); stA(0, 1, 0);
  stA(1, 0, 1); stB(1, 0, 1); stB(1, 1, 1);
  waitv<6>();
  __builtin_amdgcn_s_barrier();

  for (int t = 0; t < NT - 2; ++t) {
    const int buf = t & 1;
    PHASE_A(buf, t, true, 8);
    PHASE_B(buf, t, true, 8);
  }
  PHASE_A(0, 16, true, 8);
  PHASE_B(0, 16, false, 2);
  PHASE_A(1, 17, false, 0);
  PHASE_B(1, 17, false, 0);

#undef PHASE_A
#undef PHASE_B
#undef MFMA_QUAD

  #pragma unroll
  for (int mh = 0; mh < 2; ++mh)
    #pragma unroll
    for (int nh = 0; nh < 2; ++nh)
      #pragma unroll
      for (int mf = 0; mf < 2; ++mf)
        #pragma unroll
        for (int nf = 0; nf < 2; ++nf) {
          f32x4 v = acc[mh][nh][mf][nf];
          const int col = colBase + nh * 64 + wn * 32 + nf * 16 + lr;
          #pragma unroll
          for (int rr = 0; rr < 4; ++rr) {
            const int row = rowBase + mh * 64 + wm * 32 + mf * 16 + lkq * 4 + rr;
            const float e  = __expf(2.f * v[rr]);
            const float ht = 1.f - 2.f / (e + 1.f);
            const float o  = bf2f(omz[(size_t)row * HDIM + col]);
            const float hv = bf2f(hb[(size_t)row * KDIM + IDIM + col]);
            out[(size_t)row * HDIM + col] = o * (ht - hv);
          }
        }
}

// ---------------------------------------------------------------------------
extern "C" void kernel_launch(void* const* d_in, const int* in_sizes, int n_in,
                              void* d_out, int out_size, void* d_ws, size_t ws_size,
                              hipStream_t stream) {
  const float* t  = (const float*)d_in[0];
  const float* h  = (const float*)d_in[1];
  const float* xc = (const float*)d_in[2];
  const float* Wr = (const float*)d_in[3];
  const float* Wz = (const float*)d_in[4];
  const float* Wh = (const float*)d_in[5];
  float* out = (float*)d_out;

  u16* WB  = (u16*)d_ws;
  u16* A1  = WB + (size_t)3 * 1024 * KDIM;
  u16* A2  = A1 + (size_t)B_ROWS * KDIM;
  u16* omz = A2 + (size_t)B_ROWS * KDIM;

  convert_kernel<<<CV_BLOCKS, 256, 0, stream>>>(t, h, xc, Wr, Wz, Wh, WB, A1);

  // GEMM1: [x|h] x [W_r;W_z]^T -> r,z ; 256x256 tiles, grid 32x8 = 256, 1/CU
  gemm1_256sq<<<256, 512, 0, stream>>>(A1, WB, A1, A2, omz);

  // GEMM2: [x|r*h] x W_h^T -> out = (1-z)*(htilde - h) ; grid 64x8 = 512
  gemm2_128<<<512, 256, 0, stream>>>(A2, A1, WB + (size_t)2048 * KDIM,
                                     A1, omz, out);
}